// Round 16
// baseline (209.377 us; speedup 1.0000x reference)
//
#include <hip/hip_runtime.h>
#include <hip/hip_bf16.h>
#include <hip/hip_fp8.h>
#include <stdint.h>

#define P_B 4096
#define P_N 16384
#define P_F 768
#define P_E 512
#define NKT_F 24   // 768/32 k-tiles (bf16 packing, embed operands)
#define NP_E 16    // 512/32 k-p-groups (fp8 packing, echo operands, 32x32 frags)
#define CPAD 776   // stage LDS row pad (bf16 elems)
#define EPAD3 520  // fused-embed epilogue LDS row pad (bf16 elems)

typedef __attribute__((ext_vector_type(8))) __bf16 bf16x8;
typedef __attribute__((ext_vector_type(4))) float f32x4;
typedef __attribute__((ext_vector_type(16))) float f32x16;

__device__ __forceinline__ unsigned short bfbits(float x) {
    __bf16 h = (__bf16)x;
    union { __bf16 h; unsigned short u; } cv;
    cv.h = h;
    return cv.u;
}
__device__ __forceinline__ float bf2f(unsigned short u) {
    union { float f; unsigned int i; } cv;
    cv.i = ((unsigned int)u) << 16;
    return cv.f;
}
__device__ __forceinline__ unsigned char f8bits(float x) {
    __hip_fp8_e4m3 h(x);           // OCP e4m3 on gfx950
    return (unsigned char)h.__x;
}

// bf16 fragment-packed (gw operand): element (r,k) ->
//   (((r>>4)*NKT_F + (k>>5))*64 + ((k>>3)&3)*16 + (r&15))*8 + (k&7)
// fp8 fragment-packed (echo operands), 32x32x16 fragment layout (r16):
// 32-row blocks rb32 = r>>5; K grouped by 32 (p = k>>5).  Chunk
// (rb32, p, lane) of 16B, lane = (r&31) | (((k>>3)&1)<<5):
//   byte (r,k) -> (((r>>5)*NP_E + (k>>5))*64 + lane)*16
//                  + ((k>>4)&1)*8 + (k&7)
// i.e. per K=16 MFMA slice, lane l holds row l&31, kk = (l>>5)*8 + [0..7]
// (the 32-row generalization of the proven 16x16 pack).

// ---------------------------------------------------------------------------
// gw pack only (r14-proven).  32 blocks, r6-proven transpose.
// ---------------------------------------------------------------------------
__global__ __launch_bounds__(256) void convert_pack_kernel(
    const float* __restrict__ gw, unsigned short* __restrict__ gwpk)
{
    __shared__ unsigned short T[16 * CPAD];
    const int tid = threadIdx.x;
    const int rb = blockIdx.x;          // 0..31

    const float* src = gw + (size_t)rb * 16 * P_F;
    unsigned short* dstbase = gwpk + (size_t)rb * NKT_F * 512;

#pragma unroll
    for (int it = 0; it < 12; ++it) {
        const int flat = it * 1024 + tid * 4;
        const int row = flat / P_F;
        const int col = flat - row * P_F;
        const float4 v = *(const float4*)(src + (size_t)row * P_F + col);
        unsigned short* t = &T[row * CPAD + col];
        t[0] = bfbits(v.x); t[1] = bfbits(v.y); t[2] = bfbits(v.z); t[3] = bfbits(v.w);
    }
    __syncthreads();

#pragma unroll
    for (int it = 0; it < 6; ++it) {
        const int m = it * 256 + tid;
        const int kt = m >> 6;          // 0..23
        const int lane = m & 63;
        const int r = lane & 15;
        const int k = kt * 32 + (lane >> 4) * 8;
        const uint4 frag = *(const uint4*)(&T[r * CPAD + k]);
        *(uint4*)(dstbase + (size_t)(kt * 64 + lane) * 8) = frag;
    }
}

// ---------------------------------------------------------------------------
// Fused convert+embed (r15-proven structure, (256,2)).  r16: the fp8 packed
// store emits the 32x32-fragment layout (each block's 32 rows = exactly one
// rb32).  Everything else byte-identical to r15: inline finalize transform
// into fbuf, plain-store norm2 path, echo-zeroing by blocks 0..15.
// ---------------------------------------------------------------------------
__global__ __launch_bounds__(256, 2) void embed_pk_kernel(
    const float* __restrict__ X, const float* __restrict__ D,
    const unsigned short* __restrict__ gwpk, const float* __restrict__ gb,
    unsigned char* __restrict__ embpk8, float* __restrict__ fbuf,
    const float* __restrict__ rr, float* __restrict__ echo)
{
    __shared__ union {
        unsigned short T[32 * CPAD];    // 49.7 KB stage
        struct {
            unsigned short Es[32 * EPAD3];  // 33.3 KB epilogue stash
            float R[4][32];                 // cross-wave ssq partials
        } e;
    } sh;
    const int tid = threadIdx.x, lane = tid & 63, wave = tid >> 6;
    const int q = lane >> 4, c = lane & 15;
    const int rowTile = blockIdx.x;      // 0..639 (32 rows each; == rb32)
    const float* src = (rowTile < 128) ? (X + (size_t)rowTile * 32 * P_F)
                                       : (D + (size_t)(rowTile - 128) * 32 * P_F);

    if (rowTile < 16) echo[rowTile * 256 + tid] = 0.0f;   // zero echo for echo_pk's atomics

    // ---- stage: 32x768 fp32 -> bf16 transpose buffer ----
#pragma unroll
    for (int it = 0; it < 24; ++it) {
        const int flat = it * 1024 + tid * 4;
        const int row = flat / P_F;
        const int col = flat - row * P_F;
        const float4 v = *(const float4*)(src + (size_t)row * P_F + col);
        unsigned short* t = &sh.T[row * CPAD + col];
        t[0] = bfbits(v.x); t[1] = bfbits(v.y); t[2] = bfbits(v.z); t[3] = bfbits(v.w);
    }
    __syncthreads();

    // ---- K-loop: wave w covers cols [w*128, w*128+128) -> cb = w*8+j ----
    const unsigned short* pb[8];
#pragma unroll
    for (int j = 0; j < 8; j++)
        pb[j] = gwpk + ((size_t)(wave * 8 + j) * NKT_F * 64 + lane) * 8;

    f32x4 acc[2][8];
    const f32x4 zero = {0.f, 0.f, 0.f, 0.f};
#pragma unroll
    for (int i = 0; i < 2; i++)
#pragma unroll
        for (int j = 0; j < 8; j++) acc[i][j] = zero;

#pragma unroll
    for (int kt = 0; kt < NKT_F; ++kt) {
        bf16x8 af[2], bfr[8];
#pragma unroll
        for (int i = 0; i < 2; i++)
            af[i] = *(const bf16x8*)(&sh.T[(i * 16 + (lane & 15)) * CPAD
                                           + kt * 32 + (lane >> 4) * 8]);
#pragma unroll
        for (int j = 0; j < 8; j++) bfr[j] = *(const bf16x8*)(pb[j] + (size_t)kt * 512);
        __builtin_amdgcn_s_setprio(1);
#pragma unroll
        for (int i = 0; i < 2; i++)
#pragma unroll
            for (int j = 0; j < 8; j++)
                acc[i][j] = __builtin_amdgcn_mfma_f32_16x16x32_bf16(af[i], bfr[j], acc[i][j], 0, 0, 0);
        __builtin_amdgcn_s_setprio(0);
    }
    __syncthreads();   // done reading T; LDS becomes Es/R

    // ---- epilogue: bias, ssq (bf16 values), bf16 LDS stash ----
    float ss[2][4];
#pragma unroll
    for (int i = 0; i < 2; i++)
#pragma unroll
        for (int r = 0; r < 4; r++) ss[i][r] = 0.f;
#pragma unroll
    for (int j = 0; j < 8; j++) {
        const int lc = wave * 128 + j * 16 + c;    // 0..511
        const float bias = gb[lc];
#pragma unroll
        for (int i = 0; i < 2; i++) {
#pragma unroll
            for (int r = 0; r < 4; r++) {
                const int lr = i * 16 + q * 4 + r;  // 0..31
                const float v = acc[i][j][r] + bias;
                const unsigned short hb = bfbits(v);
                sh.e.Es[lr * EPAD3 + lc] = hb;
                const float vs = bf2f(hb);
                ss[i][r] = fmaf(vs, vs, ss[i][r]);
            }
        }
    }
#pragma unroll
    for (int i = 0; i < 2; i++)
#pragma unroll
        for (int r = 0; r < 4; r++) {
            float s = ss[i][r];
            s += __shfl_xor(s, 1);
            s += __shfl_xor(s, 2);
            s += __shfl_xor(s, 4);
            s += __shfl_xor(s, 8);
            ss[i][r] = s;
        }
    // per-wave partials -> LDS (c==0 lane of each 16-lane group writes)
    if (c == 0) {
#pragma unroll
        for (int i = 0; i < 2; i++)
#pragma unroll
            for (int r = 0; r < 4; r++)
                sh.e.R[wave][i * 16 + q * 4 + r] = ss[i][r];
    }
    __syncthreads();

    // wave 0: sum partials, apply finalize transform, plain-store weight
    if (tid < 32) {
        const float s = sh.e.R[0][tid] + sh.e.R[1][tid] + sh.e.R[2][tid] + sh.e.R[3][tid];
        const int rowg = rowTile * 32 + tid;
        const float nrm = fmaxf(sqrtf(s), 1e-12f);
        const float inv = 1.0f / nrm;
        float w = inv * inv * inv;
        if (rowTile >= 128) w *= (2.0f * rr[rowg - P_B] - 1.0f);
        fbuf[rowg] = w;
    }

    // ---- fp8 packed store, 32x32-frag layout: 16 p x 64 lanes x 16B ----
    // lane2 = h8*32 + r2 holds, for K-slice half h (byte 0/8):
    //   k = p*32 + h*16 + h8*8 + [0..7]  of row r2.
#pragma unroll
    for (int it = 0; it < 4; ++it) {
        const int m = it * 256 + tid;       // 0..1023
        const int p = m >> 6;               // 0..15
        const int lane2 = m & 63;
        const int r2 = lane2 & 31;
        const int h8 = lane2 >> 5;
        const unsigned short* e0 = &sh.e.Es[r2 * EPAD3 + p * 32 + h8 * 8];
        const unsigned short* e1 = e0 + 16;
        union { unsigned char b[16]; uint4 v; } outw;
#pragma unroll
        for (int t = 0; t < 8; t++) outw.b[t]     = f8bits(bf2f(e0[t]));
#pragma unroll
        for (int t = 0; t < 8; t++) outw.b[8 + t] = f8bits(bf2f(e1[t]));
        *(uint4*)(embpk8 + (((size_t)rowTile * NP_E + (size_t)p) * 64 + lane2) * 16) = outw.v;
    }
}

// ---------------------------------------------------------------------------
// Echo (fp8, r16: 32x32x16 fragments on the r8-locked macro-structure).
// Same supertile mapping, same barrier-free K-loop shape, same 64x16B loads
// per wave — but 128 MFMA @ ~8cyc instead of 256 @ ~4.85cyc: 17% fewer
// matrix-pipe cycles, half the instructions, 2x-longer instructions for the
// same load stream to hide under; live operand regs 32->16.  acc = 2x2
// f32x16 = 64 AGPR (unchanged).  C/D: col=lane&31,
// row=(reg&3)+8*(reg>>2)+4*(lane>>5) (m74/m101-verified, dtype-indep).
// s_setprio(1) around the MFMA cluster (r7-proven).
// ---------------------------------------------------------------------------
__global__ __launch_bounds__(256, 2) void echo_pk_kernel(
    const unsigned char* __restrict__ embpk8, const float* __restrict__ fbuf,
    float* __restrict__ echo)
{
    const int tid = threadIdx.x, lane = tid & 63, wave = tid >> 6;
    const int bid = blockIdx.x;          // 0..4095
    const int sb = bid >> 6, w = bid & 63;
    const int btile = (sb & 3) * 8 + (w & 7);    // 0..31
    const int ntile = (sb >> 2) * 8 + (w >> 3);  // 0..127
    const int row0 = btile * 128;
    const int col0 = ntile * 128;
    const int rbA0 = btile * 4 + (wave >> 1) * 2;        // rb32 units
    const int rbB0 = 128 + ntile * 4 + (wave & 1) * 2;   // De rows start at rb32 128

    const unsigned char* pa[2];
    const unsigned char* pb[2];
#pragma unroll
    for (int i = 0; i < 2; i++)
        pa[i] = embpk8 + ((size_t)(rbA0 + i) * NP_E * 64 + lane) * 16;
#pragma unroll
    for (int j = 0; j < 2; j++)
        pb[j] = embpk8 + ((size_t)(rbB0 + j) * NP_E * 64 + lane) * 16;

    f32x16 acc[2][2];
#pragma unroll
    for (int i = 0; i < 2; i++)
#pragma unroll
        for (int j = 0; j < 2; j++)
#pragma unroll
            for (int r = 0; r < 16; r++) acc[i][j][r] = 0.f;

#pragma unroll
    for (int p = 0; p < NP_E; ++p) {
        union { uint4 v; long l[2]; } ua[2], ub[2];
#pragma unroll
        for (int i = 0; i < 2; i++) ua[i].v = *(const uint4*)(pa[i] + (size_t)p * 1024);
#pragma unroll
        for (int j = 0; j < 2; j++) ub[j].v = *(const uint4*)(pb[j] + (size_t)p * 1024);
        __builtin_amdgcn_s_setprio(1);
#pragma unroll
        for (int h = 0; h < 2; h++)
#pragma unroll
            for (int i = 0; i < 2; i++)
#pragma unroll
                for (int j = 0; j < 2; j++)
                    acc[i][j] = __builtin_amdgcn_mfma_f32_32x32x16_fp8_fp8(
                        ua[i].l[h], ub[j].l[h], acc[i][j], 0, 0, 0);
        __builtin_amdgcn_s_setprio(0);
    }

    // epilogue: cube, weight by (ind^3*r2), reduce over columns, atomicAdd rows
    const float* fX = fbuf;
    const float* fD = fbuf + P_B;
    const int cl = lane & 31, hl = lane >> 5;
    float wc[2];
#pragma unroll
    for (int j = 0; j < 2; j++) wc[j] = fD[col0 + (wave & 1) * 64 + j * 32 + cl];
    float pr[2][16];
#pragma unroll
    for (int i = 0; i < 2; i++)
#pragma unroll
        for (int r = 0; r < 16; r++) pr[i][r] = 0.f;
#pragma unroll
    for (int i = 0; i < 2; i++)
#pragma unroll
        for (int j = 0; j < 2; j++)
#pragma unroll
            for (int r = 0; r < 16; r++) {
                const float v = acc[i][j][r];
                const float v3 = v * v * v;
                pr[i][r] = fmaf(v3, wc[j], pr[i][r]);
            }
#pragma unroll
    for (int i = 0; i < 2; i++)
#pragma unroll
        for (int r = 0; r < 16; r++) {
            float s = pr[i][r];
            s += __shfl_xor(s, 1);
            s += __shfl_xor(s, 2);
            s += __shfl_xor(s, 4);
            s += __shfl_xor(s, 8);
            s += __shfl_xor(s, 16);
            pr[i][r] = s;
        }
    if (cl == 0) {
#pragma unroll
        for (int i = 0; i < 2; i++)
#pragma unroll
            for (int r = 0; r < 16; r++) {
                const int rowg = row0 + (wave >> 1) * 64 + i * 32
                               + (r & 3) + 8 * (r >> 2) + 4 * hl;
                atomicAdd(&echo[rowg], pr[i][r] * fX[rowg]);
            }
    }
}

// ---------------------------------------------------------------------------
// Head: logits = echo*h_w + h_b ; preds = sigmoid(logits)
// ---------------------------------------------------------------------------
__global__ void head_kernel(const float* __restrict__ echo, const float* __restrict__ hw,
                            const float* __restrict__ hb, float* __restrict__ out)
{
    const int i = blockIdx.x * 256 + threadIdx.x;
    if (i >= P_B) return;
    const float logit = fmaf(echo[i], hw[0], hb[0]);
    out[i] = logit;
    out[P_B + i] = 1.0f / (1.0f + expf(-logit));
}

extern "C" void kernel_launch(void* const* d_in, const int* in_sizes, int n_in,
                              void* d_out, int out_size, void* d_ws, size_t ws_size,
                              hipStream_t stream)
{
    const float* X  = (const float*)d_in[0];
    const float* D  = (const float*)d_in[1];
    const float* r  = (const float*)d_in[2];
    const float* gw = (const float*)d_in[3];
    const float* gb = (const float*)d_in[4];
    const float* hw = (const float*)d_in[5];
    const float* hb = (const float*)d_in[6];
    float* out = (float*)d_out;

    char* ws = (char*)d_ws;
    const size_t gwpk_bytes   = (size_t)32 * NKT_F * 64 * 8 * 2;      //    786,432
    const size_t embpk8_bytes = (size_t)640 * NP_E * 64 * 16;         // 10,485,760

    unsigned short* gwpk   = (unsigned short*)ws;
    unsigned char*  embpk8 = (unsigned char*)(ws + gwpk_bytes);
    float* fbuf = (float*)(ws + gwpk_bytes + embpk8_bytes);           // finished weights
    float* echo = fbuf + (P_B + P_N);

    convert_pack_kernel<<<dim3(32), 256, 0, stream>>>(gw, gwpk);
    embed_pk_kernel<<<dim3(640), 256, 0, stream>>>(X, D, gwpk, gb, embpk8, fbuf, r, echo);
    echo_pk_kernel<<<dim3(4096), 256, 0, stream>>>(embpk8, fbuf, echo);
    head_kernel<<<dim3((P_B + 255) / 256), 256, 0, stream>>>(echo, hw, hb, out);
}

// Round 17
// 178.556 us; speedup vs baseline: 1.1726x; 1.1726x over previous
//
#include <hip/hip_runtime.h>
#include <hip/hip_bf16.h>
#include <hip/hip_fp8.h>
#include <stdint.h>

#define P_B 4096
#define P_N 16384
#define P_F 768
#define P_E 512
#define NKT_F 24   // 768/32 k-tiles (bf16 packing, embed operands)
#define NKTP_E 8   // 512/64 k-tile-pairs (fp8 packing, echo operands)
#define CPAD 776   // stage LDS row pad (bf16 elems)
#define EPAD3 520  // fused-embed epilogue LDS row pad (bf16 elems)

typedef __attribute__((ext_vector_type(8))) __bf16 bf16x8;
typedef __attribute__((ext_vector_type(4))) float f32x4;

__device__ __forceinline__ unsigned short bfbits(float x) {
    __bf16 h = (__bf16)x;
    union { __bf16 h; unsigned short u; } cv;
    cv.h = h;
    return cv.u;
}
__device__ __forceinline__ float bf2f(unsigned short u) {
    union { float f; unsigned int i; } cv;
    cv.i = ((unsigned int)u) << 16;
    return cv.f;
}
__device__ __forceinline__ unsigned char f8bits(float x) {
    __hip_fp8_e4m3 h(x);           // OCP e4m3 on gfx950
    return (unsigned char)h.__x;
}

// bf16 fragment-packed (gw operand): element (r,k) ->
//   (((r>>4)*NKT_F + (k>>5))*64 + ((k>>3)&3)*16 + (r&15))*8 + (k&7)
// fp8 fragment-packed (echo operands), K grouped by 64: element (r,k) -> byte
//   (((r>>4)*NKTP_E + (k>>6))*64 + (((k>>3)&3)*16 + (r&15)))*16
//     + ((k>>5)&1)*8 + (k&7)

// ---------------------------------------------------------------------------
// gw pack only (r14-proven).  32 blocks, r6-proven transpose.
// ---------------------------------------------------------------------------
__global__ __launch_bounds__(256) void convert_pack_kernel(
    const float* __restrict__ gw, unsigned short* __restrict__ gwpk)
{
    __shared__ unsigned short T[16 * CPAD];
    const int tid = threadIdx.x;
    const int rb = blockIdx.x;          // 0..31

    const float* src = gw + (size_t)rb * 16 * P_F;
    unsigned short* dstbase = gwpk + (size_t)rb * NKT_F * 512;

#pragma unroll
    for (int it = 0; it < 12; ++it) {
        const int flat = it * 1024 + tid * 4;
        const int row = flat / P_F;
        const int col = flat - row * P_F;
        const float4 v = *(const float4*)(src + (size_t)row * P_F + col);
        unsigned short* t = &T[row * CPAD + col];
        t[0] = bfbits(v.x); t[1] = bfbits(v.y); t[2] = bfbits(v.z); t[3] = bfbits(v.w);
    }
    __syncthreads();

#pragma unroll
    for (int it = 0; it < 6; ++it) {
        const int m = it * 256 + tid;
        const int kt = m >> 6;          // 0..23
        const int lane = m & 63;
        const int r = lane & 15;
        const int k = kt * 32 + (lane >> 4) * 8;
        const uint4 frag = *(const uint4*)(&T[r * CPAD + k]);
        *(uint4*)(dstbase + (size_t)(kt * 64 + lane) * 8) = frag;
    }
}

// ---------------------------------------------------------------------------
// Fused convert+embed (r15-verified optimum, (256,2)): serial bf16 stage,
// barrier-free K-loop (2x8 acc), inline finalize transform into fbuf
// (plain store — block owns its 32 rows), echo-zeroing by blocks 0..15,
// fp8 packed store in the 16x16 K=64 fragment layout.
// r16's 32x32-frag variant regressed echo 61->91us (4 acc chains x 2-deep
// dependent vs 16 independent — MFMA-pipe ILP starvation); reverted.
// ---------------------------------------------------------------------------
__global__ __launch_bounds__(256, 2) void embed_pk_kernel(
    const float* __restrict__ X, const float* __restrict__ D,
    const unsigned short* __restrict__ gwpk, const float* __restrict__ gb,
    unsigned char* __restrict__ embpk8, float* __restrict__ fbuf,
    const float* __restrict__ rr, float* __restrict__ echo)
{
    __shared__ union {
        unsigned short T[32 * CPAD];    // 49.7 KB stage
        struct {
            unsigned short Es[32 * EPAD3];  // 33.3 KB epilogue stash
            float R[4][32];                 // cross-wave ssq partials
        } e;
    } sh;
    const int tid = threadIdx.x, lane = tid & 63, wave = tid >> 6;
    const int q = lane >> 4, c = lane & 15;
    const int rowTile = blockIdx.x;      // 0..639 (32 rows each)
    const float* src = (rowTile < 128) ? (X + (size_t)rowTile * 32 * P_F)
                                       : (D + (size_t)(rowTile - 128) * 32 * P_F);

    if (rowTile < 16) echo[rowTile * 256 + tid] = 0.0f;   // zero echo for echo_pk's atomics

    // ---- stage: 32x768 fp32 -> bf16 transpose buffer ----
#pragma unroll
    for (int it = 0; it < 24; ++it) {
        const int flat = it * 1024 + tid * 4;
        const int row = flat / P_F;
        const int col = flat - row * P_F;
        const float4 v = *(const float4*)(src + (size_t)row * P_F + col);
        unsigned short* t = &sh.T[row * CPAD + col];
        t[0] = bfbits(v.x); t[1] = bfbits(v.y); t[2] = bfbits(v.z); t[3] = bfbits(v.w);
    }
    __syncthreads();

    // ---- K-loop: wave w covers cols [w*128, w*128+128) -> cb = w*8+j ----
    const unsigned short* pb[8];
#pragma unroll
    for (int j = 0; j < 8; j++)
        pb[j] = gwpk + ((size_t)(wave * 8 + j) * NKT_F * 64 + lane) * 8;

    f32x4 acc[2][8];
    const f32x4 zero = {0.f, 0.f, 0.f, 0.f};
#pragma unroll
    for (int i = 0; i < 2; i++)
#pragma unroll
        for (int j = 0; j < 8; j++) acc[i][j] = zero;

#pragma unroll
    for (int kt = 0; kt < NKT_F; ++kt) {
        bf16x8 af[2], bfr[8];
#pragma unroll
        for (int i = 0; i < 2; i++)
            af[i] = *(const bf16x8*)(&sh.T[(i * 16 + (lane & 15)) * CPAD
                                           + kt * 32 + (lane >> 4) * 8]);
#pragma unroll
        for (int j = 0; j < 8; j++) bfr[j] = *(const bf16x8*)(pb[j] + (size_t)kt * 512);
        __builtin_amdgcn_s_setprio(1);
#pragma unroll
        for (int i = 0; i < 2; i++)
#pragma unroll
            for (int j = 0; j < 8; j++)
                acc[i][j] = __builtin_amdgcn_mfma_f32_16x16x32_bf16(af[i], bfr[j], acc[i][j], 0, 0, 0);
        __builtin_amdgcn_s_setprio(0);
    }
    __syncthreads();   // done reading T; LDS becomes Es/R

    // ---- epilogue: bias, ssq (bf16 values), bf16 LDS stash ----
    float ss[2][4];
#pragma unroll
    for (int i = 0; i < 2; i++)
#pragma unroll
        for (int r = 0; r < 4; r++) ss[i][r] = 0.f;
#pragma unroll
    for (int j = 0; j < 8; j++) {
        const int lc = wave * 128 + j * 16 + c;    // 0..511
        const float bias = gb[lc];
#pragma unroll
        for (int i = 0; i < 2; i++) {
#pragma unroll
            for (int r = 0; r < 4; r++) {
                const int lr = i * 16 + q * 4 + r;  // 0..31
                const float v = acc[i][j][r] + bias;
                const unsigned short hb = bfbits(v);
                sh.e.Es[lr * EPAD3 + lc] = hb;
                const float vs = bf2f(hb);
                ss[i][r] = fmaf(vs, vs, ss[i][r]);
            }
        }
    }
#pragma unroll
    for (int i = 0; i < 2; i++)
#pragma unroll
        for (int r = 0; r < 4; r++) {
            float s = ss[i][r];
            s += __shfl_xor(s, 1);
            s += __shfl_xor(s, 2);
            s += __shfl_xor(s, 4);
            s += __shfl_xor(s, 8);
            ss[i][r] = s;
        }
    // per-wave partials -> LDS (c==0 lane of each 16-lane group writes)
    if (c == 0) {
#pragma unroll
        for (int i = 0; i < 2; i++)
#pragma unroll
            for (int r = 0; r < 4; r++)
                sh.e.R[wave][i * 16 + q * 4 + r] = ss[i][r];
    }
    __syncthreads();

    // wave 0: sum partials, apply finalize transform, plain-store weight
    if (tid < 32) {
        const float s = sh.e.R[0][tid] + sh.e.R[1][tid] + sh.e.R[2][tid] + sh.e.R[3][tid];
        const int rowg = rowTile * 32 + tid;
        const float nrm = fmaxf(sqrtf(s), 1e-12f);
        const float inv = 1.0f / nrm;
        float w = inv * inv * inv;
        if (rowTile >= 128) w *= (2.0f * rr[rowg - P_B] - 1.0f);
        fbuf[rowg] = w;
    }

    // ---- fp8 packed store: 2 rbl x 8 ktp x 64 lanes x 16B, 4 iters ----
#pragma unroll
    for (int it = 0; it < 4; ++it) {
        const int m = it * 256 + tid;       // 0..1023
        const int rbl = m >> 9;             // 0..1
        const int rest = m & 511;
        const int ktpl = rest >> 6;         // 0..7
        const int lane2 = rest & 63;
        const int r2 = lane2 & 15;
        const int q2 = lane2 >> 4;
        const int lr = rbl * 16 + r2;
        const unsigned short* e0 = &sh.e.Es[lr * EPAD3 + ktpl * 64 + q2 * 8];
        const unsigned short* e1 = e0 + 32;
        union { unsigned char b[16]; uint4 v; } outw;
#pragma unroll
        for (int t = 0; t < 8; t++) outw.b[t]     = f8bits(bf2f(e0[t]));
#pragma unroll
        for (int t = 0; t < 8; t++) outw.b[8 + t] = f8bits(bf2f(e1[t]));
        const size_t rb = (size_t)(rowTile * 2 + rbl);
        *(uint4*)(embpk8 + ((rb * NKTP_E + (size_t)ktpl) * 64 + lane2) * 16) = outw.v;
    }
}

// ---------------------------------------------------------------------------
// Echo (fp8, r8-verified BYTE-IDENTICAL source AND signature: 59-60 us,
// MfmaUtil 46%, VGPR 60 -> 124 unified regs -> 4 waves/SIMD, no spill).
// Supertile mapping + barrier-free fragment K-loop; s_setprio(1) around the
// MFMA cluster.  fbuf holds pre-finalized weights (embed applies the
// transform).  DO NOT TOUCH — r14 (epilogue tail) and r16 (32x32 shape)
// both proved any change to this kernel's K-loop context regresses it.
// ---------------------------------------------------------------------------
__global__ __launch_bounds__(256, 2) void echo_pk_kernel(
    const unsigned char* __restrict__ embpk8, const float* __restrict__ fbuf,
    float* __restrict__ echo)
{
    const int tid = threadIdx.x, lane = tid & 63, wave = tid >> 6;
    const int q = lane >> 4, c = lane & 15;
    const int bid = blockIdx.x;          // 0..4095
    const int sb = bid >> 6, w = bid & 63;
    const int btile = (sb & 3) * 8 + (w & 7);    // 0..31
    const int ntile = (sb >> 2) * 8 + (w >> 3);  // 0..127
    const int row0 = btile * 128;
    const int col0 = ntile * 128;
    const int rbA0 = btile * 8 + (wave >> 1) * 4;
    const int rbB0 = 256 + ntile * 8 + (wave & 1) * 4;   // De rows start at rb 256

    const unsigned char* pa[4];
    const unsigned char* pb[4];
#pragma unroll
    for (int i = 0; i < 4; i++)
        pa[i] = embpk8 + ((size_t)(rbA0 + i) * NKTP_E * 64 + lane) * 16;
#pragma unroll
    for (int j = 0; j < 4; j++)
        pb[j] = embpk8 + ((size_t)(rbB0 + j) * NKTP_E * 64 + lane) * 16;

    f32x4 acc[4][4];
    const f32x4 zero = {0.f, 0.f, 0.f, 0.f};
#pragma unroll
    for (int i = 0; i < 4; i++)
#pragma unroll
        for (int j = 0; j < 4; j++) acc[i][j] = zero;

#pragma unroll
    for (int ktp = 0; ktp < NKTP_E; ++ktp) {
        union { uint4 v; long l[2]; } ua[4], ub[4];
#pragma unroll
        for (int i = 0; i < 4; i++) ua[i].v = *(const uint4*)(pa[i] + (size_t)ktp * 1024);
#pragma unroll
        for (int j = 0; j < 4; j++) ub[j].v = *(const uint4*)(pb[j] + (size_t)ktp * 1024);
        __builtin_amdgcn_s_setprio(1);
#pragma unroll
        for (int h = 0; h < 2; h++)
#pragma unroll
            for (int i = 0; i < 4; i++)
#pragma unroll
                for (int j = 0; j < 4; j++)
                    acc[i][j] = __builtin_amdgcn_mfma_f32_16x16x32_fp8_fp8(
                        ua[i].l[h], ub[j].l[h], acc[i][j], 0, 0, 0);
        __builtin_amdgcn_s_setprio(0);
    }

    // epilogue: cube, weight by (ind^3*r2), reduce over columns, atomicAdd rows
    const float* fX = fbuf;
    const float* fD = fbuf + P_B;
    float wc[4];
#pragma unroll
    for (int j = 0; j < 4; j++) wc[j] = fD[col0 + (wave & 1) * 64 + j * 16 + c];
    float p[4][4];
#pragma unroll
    for (int i = 0; i < 4; i++)
#pragma unroll
        for (int r = 0; r < 4; r++) p[i][r] = 0.f;
#pragma unroll
    for (int i = 0; i < 4; i++)
#pragma unroll
        for (int j = 0; j < 4; j++)
#pragma unroll
            for (int r = 0; r < 4; r++) {
                const float v = acc[i][j][r];
                const float v3 = v * v * v;
                p[i][r] = fmaf(v3, wc[j], p[i][r]);
            }
#pragma unroll
    for (int i = 0; i < 4; i++)
#pragma unroll
        for (int r = 0; r < 4; r++) {
            float s = p[i][r];
            s += __shfl_xor(s, 1);
            s += __shfl_xor(s, 2);
            s += __shfl_xor(s, 4);
            s += __shfl_xor(s, 8);
            p[i][r] = s;
        }
    if (c == 0) {
#pragma unroll
        for (int i = 0; i < 4; i++)
#pragma unroll
            for (int r = 0; r < 4; r++) {
                const int rowg = row0 + (wave >> 1) * 64 + i * 16 + q * 4 + r;
                atomicAdd(&echo[rowg], p[i][r] * fX[rowg]);
            }
    }
}

// ---------------------------------------------------------------------------
// Head: logits = echo*h_w + h_b ; preds = sigmoid(logits)
// ---------------------------------------------------------------------------
__global__ void head_kernel(const float* __restrict__ echo, const float* __restrict__ hw,
                            const float* __restrict__ hb, float* __restrict__ out)
{
    const int i = blockIdx.x * 256 + threadIdx.x;
    if (i >= P_B) return;
    const float logit = fmaf(echo[i], hw[0], hb[0]);
    out[i] = logit;
    out[P_B + i] = 1.0f / (1.0f + expf(-logit));
}

extern "C" void kernel_launch(void* const* d_in, const int* in_sizes, int n_in,
                              void* d_out, int out_size, void* d_ws, size_t ws_size,
                              hipStream_t stream)
{
    const float* X  = (const float*)d_in[0];
    const float* D  = (const float*)d_in[1];
    const float* r  = (const float*)d_in[2];
    const float* gw = (const float*)d_in[3];
    const float* gb = (const float*)d_in[4];
    const float* hw = (const float*)d_in[5];
    const float* hb = (const float*)d_in[6];
    float* out = (float*)d_out;

    char* ws = (char*)d_ws;
    const size_t gwpk_bytes   = (size_t)32 * NKT_F * 64 * 8 * 2;      //    786,432
    const size_t embpk8_bytes = (size_t)1280 * NKTP_E * 64 * 16;      // 10,485,760

    unsigned short* gwpk   = (unsigned short*)ws;
    unsigned char*  embpk8 = (unsigned char*)(ws + gwpk_bytes);
    float* fbuf = (float*)(ws + gwpk_bytes + embpk8_bytes);           // finished weights
    float* echo = fbuf + (P_B + P_N);

    convert_pack_kernel<<<dim3(32), 256, 0, stream>>>(gw, gwpk);
    embed_pk_kernel<<<dim3(640), 256, 0, stream>>>(X, D, gwpk, gb, embpk8, fbuf, r, echo);
    echo_pk_kernel<<<dim3(4096), 256, 0, stream>>>(embpk8, fbuf, echo);
    head_kernel<<<dim3((P_B + 255) / 256), 256, 0, stream>>>(echo, hw, hb, out);
}